// Round 10
// baseline (599.117 us; speedup 1.0000x reference)
//
#include <hip/hip_runtime.h>
#include <stdint.h>

typedef __attribute__((ext_vector_type(8))) short short8;
typedef __attribute__((ext_vector_type(4))) float f32x4;
typedef __attribute__((ext_vector_type(4))) _Float16 half4;
typedef __attribute__((ext_vector_type(2))) _Float16 half2v;
typedef __attribute__((ext_vector_type(4))) int i32x4;

struct us4 { unsigned short x, y, z, w; };

__device__ __forceinline__ float b2f(unsigned short u){
  union { unsigned int i; float f; } x; x.i = ((unsigned int)u) << 16; return x.f;
}
__device__ __forceinline__ unsigned short f2b(float f){
  union { float f; unsigned int i; } x; x.f = f;
  unsigned int i = x.i;
  unsigned int r = (i + 0x7FFFu + ((i >> 16) & 1u)) >> 16;
  return (unsigned short)r;
}
__device__ __forceinline__ unsigned short f2h(float f){
  _Float16 h = (_Float16)f;
  union { _Float16 h; unsigned short u; } c; c.h = h; return c.u;
}
__device__ __forceinline__ float sane(float v){
  return fminf(fmaxf(v, -1e30f), 1e30f);
}
// clamp logit: NaN -> -60, range +-60 (exp-safe; softmax invariant to shift)
__device__ __forceinline__ float lclamp(float v){
  return fminf(fmaxf(v, -60.f), 60.f);
}
__device__ __forceinline__ float ldin(const void* p, size_t i, int f32){
  return f32 ? ((const float*)p)[i] : b2f(((const unsigned short*)p)[i]);
}
__device__ __forceinline__ float dot4h(half2v a0, half2v a1, half2v b0, half2v b1){
#if __has_builtin(__builtin_amdgcn_fdot2)
  return __builtin_amdgcn_fdot2(a0, b0, __builtin_amdgcn_fdot2(a1, b1, 0.f, false), false);
#else
  return (float)a0.x*(float)b0.x + (float)a0.y*(float)b0.y
       + (float)a1.x*(float)b1.x + (float)a1.y*(float)b1.y;
#endif
}
// async global->LDS, 16B per lane; lds dest = wave-uniform base + lane*16
__device__ __forceinline__ void gload_lds16(const void* g, void* l){
  __builtin_amdgcn_global_load_lds(
      (const __attribute__((address_space(1))) void*)g,
      (__attribute__((address_space(3))) void*)l, 16, 0, 0);
}

// ---------------- dtype discriminator ----------------
__global__ void k_flag(const unsigned short* __restrict__ xu, int* __restrict__ flag){
  __shared__ int cnt;
  if (threadIdx.x == 0) cnt = 0;
  __syncthreads();
  unsigned u = xu[2 * threadIdx.x];
  int e = (u >> 7) & 0xFF;
  if (e >= 97 && e <= 132) atomicAdd(&cnt, 1);
  __syncthreads();
  if (threadIdx.x == 0) flag[0] = (cnt >= 192) ? 0 : 1;   // 0=bf16, 1=fp32
}

// ---------------- x -> bf16 canonical copy (vectorized) ----------------
__global__ void k_cvt(const void* __restrict__ xin, unsigned short* __restrict__ xb,
                      int n4, const int* __restrict__ flagp){
  int f32 = *flagp;
  int i = blockIdx.x * 256 + threadIdx.x;
  if (i < n4){
    if (f32){
      float4 v = ((const float4*)xin)[i];
      us4 o = { f2b(v.x), f2b(v.y), f2b(v.z), f2b(v.w) };
      ((us4*)xb)[i] = o;
    } else {
      ((us4*)xb)[i] = ((const us4*)xin)[i];
    }
  }
}

// ---------------- CSR build (parallel scan), 4-aligned padded segments ----------------
__global__ void k_deg(const int* __restrict__ ei, int E, int N, int* __restrict__ deg){
  int e = blockIdx.x * 256 + threadIdx.x;
  if (e < E){
    unsigned d = (unsigned)ei[E + e];
    if (d < (unsigned)N) atomicAdd(&deg[d], 1);
  }
}

__device__ __forceinline__ int pad4(int d){ return (d + 3) & ~3; }

// block b sums padded deg[b*1024 .. +1023] -> bsum[b]   (256 threads)
__global__ void k_bsum(const int* __restrict__ deg, int N, int* __restrict__ bsum){
  int b = blockIdx.x, t = threadIdx.x;
  int i0 = b * 1024 + t * 4;
  int s = 0;
  if (i0 + 4 <= N){
    int4 v = *(const int4*)&deg[i0];
    s = pad4(v.x) + pad4(v.y) + pad4(v.z) + pad4(v.w);
  } else {
    #pragma unroll
    for (int j = 0; j < 4; ++j){ int i = i0 + j; if (i < N) s += pad4(deg[i]); }
  }
  #pragma unroll
  for (int off = 32; off; off >>= 1) s += __shfl_xor(s, off);
  __shared__ int ws[4];
  if ((t & 63) == 0) ws[t >> 6] = s;
  __syncthreads();
  if (t == 0) bsum[b] = ws[0] + ws[1] + ws[2] + ws[3];
}

// one wave: exclusive scan of nb block sums -> boff; rowptr[N] = total   (64 threads)
__global__ void k_bscan(const int* __restrict__ bsum, int nb,
                        int* __restrict__ boff, int* __restrict__ rowptr, int N){
  int t = threadIdx.x;
  if (nb <= 64){
    int v = (t < nb) ? bsum[t] : 0;
    int inc = v;
    #pragma unroll
    for (int off = 1; off < 64; off <<= 1){
      int u = __shfl_up(inc, off);
      if (t >= off) inc += u;
    }
    if (t < nb) boff[t] = inc - v;
    if (t == 63) rowptr[N] = inc;   // lane 63 holds grand total (padded)
  } else {
    if (t == 0){
      int run = 0;
      for (int i = 0; i < nb; ++i){ boff[i] = run; run += bsum[i]; }
      rowptr[N] = run;
    }
  }
}

// block b: intra-block exclusive scan of padded deg; write rowptr (padded starts) + cursor
__global__ void k_rowptr(const int* __restrict__ deg, const int* __restrict__ boff,
                         int N, int* __restrict__ rowptr, int* __restrict__ cursor){
  int b = blockIdx.x, t = threadIdx.x;
  int i0 = b * 1024 + t * 4;
  int d0 = 0, d1 = 0, d2 = 0, d3 = 0;
  if (i0 + 4 <= N){
    int4 v = *(const int4*)&deg[i0];
    d0 = v.x; d1 = v.y; d2 = v.z; d3 = v.w;
  } else {
    if (i0     < N) d0 = deg[i0];
    if (i0 + 1 < N) d1 = deg[i0 + 1];
    if (i0 + 2 < N) d2 = deg[i0 + 2];
    if (i0 + 3 < N) d3 = deg[i0 + 3];
  }
  int p0 = pad4(d0), p1 = pad4(d1), p2 = pad4(d2), p3 = pad4(d3);
  int s = p0 + p1 + p2 + p3;
  int lane = t & 63, w = t >> 6;
  int inc = s;
  #pragma unroll
  for (int off = 1; off < 64; off <<= 1){
    int u = __shfl_up(inc, off);
    if (lane >= off) inc += u;
  }
  int wex = inc - s;   // wave-exclusive prefix
  __shared__ int wtot[4];
  if (lane == 63) wtot[w] = inc;
  __syncthreads();
  int cross = 0;
  for (int i = 0; i < w; ++i) cross += wtot[i];
  int basev = boff[b] + cross + wex;
  int r0 = basev, r1 = basev + p0, r2 = r1 + p1, r3 = r2 + p2;
  if (i0 + 4 <= N){
    int4 o = { r0, r1, r2, r3 };
    *(int4*)&rowptr[i0] = o;
    *(int4*)&cursor[i0] = o;
  } else {
    if (i0     < N){ rowptr[i0]   = r0; cursor[i0]   = r0; }
    if (i0 + 1 < N){ rowptr[i0+1] = r1; cursor[i0+1] = r1; }
    if (i0 + 2 < N){ rowptr[i0+2] = r2; cursor[i0+2] = r2; }
    if (i0 + 3 < N){ rowptr[i0+3] = r3; cursor[i0+3] = r3; }
  }
}

// srcs[] stores BYTE offsets into the interleaved kv buffer (s*1024), clamped here.
__global__ void k_scatter(const int* __restrict__ ei, int E, int N, int Epad,
                          int* __restrict__ cursor, int* __restrict__ srcs){
  int e = blockIdx.x * 256 + threadIdx.x;
  if (e < E){
    unsigned d = (unsigned)ei[E + e];
    if (d < (unsigned)N){
      int pos = atomicAdd(&cursor[d], 1);
      if ((unsigned)pos < (unsigned)Epad){
        unsigned s = (unsigned)ei[e];
        srcs[pos] = (s < (unsigned)N) ? (int)(s * 1024u) : 0;
      }
    }
  }
}

// ---------------- weight pack: WT[cg][k] = W_mat[k][c] (bf16), bias as float ----------------
__global__ void k_pack(const void* __restrict__ Wq, const void* __restrict__ bq,
                       const void* __restrict__ Wk, const void* __restrict__ bk,
                       const void* __restrict__ Wv, const void* __restrict__ bv,
                       const void* __restrict__ Ws, const void* __restrict__ bs,
                       unsigned short* __restrict__ WT, float* __restrict__ bias,
                       int Mq, int Ms, int K, const int* __restrict__ flagp){
  int f32 = *flagp;
  int cg = blockIdx.x;
  int k  = threadIdx.x;
  int mat, c, mc;
  if (cg < 3 * Mq){ mat = cg / Mq; c = cg % Mq; mc = Mq; }
  else if (cg < 3 * Mq + Ms){ mat = 3; c = cg - 3 * Mq; mc = Ms; }
  else { mat = 4; c = 0; mc = 1; }
  const void* W = (mat==0)?Wq:(mat==1)?Wk:(mat==2)?Wv:(mat==3)?Ws:(const void*)0;
  WT[(size_t)cg * K + k] = (mat < 4) ? f2b(ldin(W, (size_t)k * mc + c, f32)) : (unsigned short)0;
  if (k == 0){
    const void* B = (mat==0)?bq:(mat==1)?bk:(mat==2)?bv:(mat==3)?bs:(const void*)0;
    bias[cg] = (mat < 4) ? ldin(B, c, f32) : 0.f;
  }
}

// ---------------- GEMM: 64-row x 256-col tile per block (split grid),
// per-K-step async global_load_lds staging of A-chunk (4KB) + B-chunk (16KB).
// Clds overlays the staging region after the K-loop. f16 outputs, kv interleaved.
// Layers 1/2 (Mout=1024): grid = rb*4; it = bid%4:
//   it0: q blks 0-3 | it1: k0,k1,v0,v1 | it2: k2,k3,v2,v3 | it3: x blks 0-3
// Layer 3 (Mout=256): grid = rb; single iteration = q,k,v,x across waves.
__global__ __launch_bounds__(256) void k_gemm(const unsigned short* __restrict__ A,
                                              const unsigned short* __restrict__ WT,
                                              const float* __restrict__ bias,
                                              unsigned short* __restrict__ qout,
                                              char* __restrict__ kvout,
                                              unsigned short* __restrict__ xout,
                                              int N, int Mout, int secshift){
  // Achk[64][32] (4KB) + Blds[256][32] (16KB) = 20.5KB; Clds[32][276] overlays.
  __shared__ __align__(16) unsigned short sh[64*32 + 256*32];
  unsigned short* Achk = sh;            // [64][32]
  unsigned short* Blds = sh + 64*32;    // [256][32], row r = block-col r
  auto Clds = (unsigned short(*)[276])sh;   // overlay after K-loop
  int tid = threadIdx.x, wid = tid >> 6, lane = tid & 63;
  int l15 = lane & 15, l4 = lane >> 4;
  int nit = Mout >> 8;   // 4 (layers 1/2) or 1 (layer 3)
  int it = blockIdx.x % nit;
  int row0 = (blockIdx.x / nit) * 64;
  int secw = 1 << secshift;
  int sec, blk;
  if (nit == 1){ sec = wid; blk = 0; }
  else if (it == 0){ sec = 0; blk = wid; }
  else if (it == 3){ sec = 3; blk = wid; }
  else { sec = (wid < 2) ? 1 : 2; blk = (it - 1) * 2 + (wid & 1); }
  int cbf = sec * secw + blk * 64;

  // per-lane staging sources (advance by k0 each step)
  int sr = lane >> 2, sc = lane & 3;   // 16 rows x 4 chunks(16B) per wave-call
  int arow = row0 + wid * 16 + sr; if (arow >= N) arow = N - 1;
  const unsigned short* Ag = A + (size_t)arow * 256 + sc * 8;
  const unsigned short* Bg[4];
  #pragma unroll
  for (int j = 0; j < 4; ++j){
    int r = wid * 64 + j * 16 + sr;   // block-col this lane stages
    int gcol;
    if (nit == 1 || it == 0) gcol = r;
    else if (it == 3)        gcol = 768 + r;
    else if (it == 1)        gcol = r + (r < 128 ? 256 : 384);
    else                     gcol = r + (r < 128 ? 384 : 512);
    Bg[j] = WT + (size_t)gcol * 256 + sc * 8;
  }
  unsigned short* AldsD = Achk + (wid * 16) * 32;   // wave-uniform dests
  unsigned short* BldsD = Blds + (wid * 64) * 32;

  f32x4 acc[4][4] = {};
  for (int k0 = 0; k0 < 256; k0 += 32){
    gload_lds16(Ag + k0, AldsD);
    gload_lds16(Bg[0] + k0, BldsD);
    gload_lds16(Bg[1] + k0, BldsD + 16*32);
    gload_lds16(Bg[2] + k0, BldsD + 32*32);
    gload_lds16(Bg[3] + k0, BldsD + 48*32);
    __syncthreads();   // drain staging; chunk visible to all waves
    short8 a0 = *(const short8*)&Achk[(     l15)*32 + l4*8];
    short8 a1 = *(const short8*)&Achk[(16 + l15)*32 + l4*8];
    short8 a2 = *(const short8*)&Achk[(32 + l15)*32 + l4*8];
    short8 a3 = *(const short8*)&Achk[(48 + l15)*32 + l4*8];
    short8 b0 = *(const short8*)&Blds[(wid*64      + l15)*32 + l4*8];
    short8 b1 = *(const short8*)&Blds[(wid*64 + 16 + l15)*32 + l4*8];
    short8 b2 = *(const short8*)&Blds[(wid*64 + 32 + l15)*32 + l4*8];
    short8 b3 = *(const short8*)&Blds[(wid*64 + 48 + l15)*32 + l4*8];
    acc[0][0] = __builtin_amdgcn_mfma_f32_16x16x32_bf16(a0, b0, acc[0][0], 0,0,0);
    acc[0][1] = __builtin_amdgcn_mfma_f32_16x16x32_bf16(a0, b1, acc[0][1], 0,0,0);
    acc[0][2] = __builtin_amdgcn_mfma_f32_16x16x32_bf16(a0, b2, acc[0][2], 0,0,0);
    acc[0][3] = __builtin_amdgcn_mfma_f32_16x16x32_bf16(a0, b3, acc[0][3], 0,0,0);
    acc[1][0] = __builtin_amdgcn_mfma_f32_16x16x32_bf16(a1, b0, acc[1][0], 0,0,0);
    acc[1][1] = __builtin_amdgcn_mfma_f32_16x16x32_bf16(a1, b1, acc[1][1], 0,0,0);
    acc[1][2] = __builtin_amdgcn_mfma_f32_16x16x32_bf16(a1, b2, acc[1][2], 0,0,0);
    acc[1][3] = __builtin_amdgcn_mfma_f32_16x16x32_bf16(a1, b3, acc[1][3], 0,0,0);
    acc[2][0] = __builtin_amdgcn_mfma_f32_16x16x32_bf16(a2, b0, acc[2][0], 0,0,0);
    acc[2][1] = __builtin_amdgcn_mfma_f32_16x16x32_bf16(a2, b1, acc[2][1], 0,0,0);
    acc[2][2] = __builtin_amdgcn_mfma_f32_16x16x32_bf16(a2, b2, acc[2][2], 0,0,0);
    acc[2][3] = __builtin_amdgcn_mfma_f32_16x16x32_bf16(a2, b3, acc[2][3], 0,0,0);
    acc[3][0] = __builtin_amdgcn_mfma_f32_16x16x32_bf16(a3, b0, acc[3][0], 0,0,0);
    acc[3][1] = __builtin_amdgcn_mfma_f32_16x16x32_bf16(a3, b1, acc[3][1], 0,0,0);
    acc[3][2] = __builtin_amdgcn_mfma_f32_16x16x32_bf16(a3, b2, acc[3][2], 0,0,0);
    acc[3][3] = __builtin_amdgcn_mfma_f32_16x16x32_bf16(a3, b3, acc[3][3], 0,0,0);
    __syncthreads();   // all waves done reading before next step's staging overwrites
  }
  int strow = tid >> 3, stchunk = tid & 7;
  #pragma unroll
  for (int ph = 0; ph < 2; ++ph){
    #pragma unroll
    for (int rt2 = 0; rt2 < 2; ++rt2){
      int rt = ph*2 + rt2;
      #pragma unroll
      for (int ct = 0; ct < 4; ++ct){
        float bv = bias[cbf + ct*16 + l15];
        #pragma unroll
        for (int r = 0; r < 4; ++r)
          Clds[rt2*16 + l4*4 + r][wid*64 + ct*16 + l15] = f2h(acc[rt][ct][r] + bv);
      }
    }
    __syncthreads();
    int grow = row0 + ph*32 + strow;
    if (grow < N){
      if (nit == 4){
        if (it == 0 || it == 3){
          unsigned short* Bp = (it == 0) ? qout : xout;
          int g0 = stchunk * 32;
          unsigned short* dst = Bp + (size_t)grow * secw + g0;
          const unsigned short* srcp = &Clds[strow][g0];
          #pragma unroll
          for (int j = 0; j < 4; ++j)
            *(short8*)(dst + j*8) = *(const short8*)(srcp + j*8);
        } else {
          int secbase = (it == 1) ? 0 : 128;
          int scl = stchunk * 16;
          char* dstb = kvout + (size_t)grow * 1024 + (size_t)(secbase + scl) * 4;
          const unsigned short* kp = &Clds[strow][scl];
          const unsigned short* vp = &Clds[strow][128 + scl];
          #pragma unroll
          for (int g2 = 0; g2 < 4; ++g2){
            union { unsigned long long u[2]; i32x4 v; } st;
            st.u[0] = *(const unsigned long long*)(kp + g2*4);
            st.u[1] = *(const unsigned long long*)(vp + g2*4);
            *(i32x4*)(dstb + g2*16) = st.v;
          }
        }
      } else {
        // layer 3: q | kv | x mixed in one iteration
        if (stchunk < 2){
          int g0 = stchunk * 32;
          unsigned short* dst = qout + (size_t)grow * secw + g0;
          const unsigned short* srcp = &Clds[strow][g0];
          #pragma unroll
          for (int j = 0; j < 4; ++j)
            *(short8*)(dst + j*8) = *(const short8*)(srcp + j*8);
        } else if (stchunk < 6){
          int scl = (stchunk - 2) * 16;
          char* dstb = kvout + (size_t)grow * 256 + (size_t)scl * 4;
          const unsigned short* kp = &Clds[strow][64 + scl];
          const unsigned short* vp = &Clds[strow][128 + scl];
          #pragma unroll
          for (int g2 = 0; g2 < 4; ++g2){
            union { unsigned long long u[2]; i32x4 v; } st;
            st.u[0] = *(const unsigned long long*)(kp + g2*4);
            st.u[1] = *(const unsigned long long*)(vp + g2*4);
            *(i32x4*)(dstb + g2*16) = st.v;
          }
        } else {
          int g0 = (stchunk - 6) * 32;
          unsigned short* dst = xout + (size_t)grow * secw + g0;
          const unsigned short* srcp = &Clds[strow][192 + g0];
          #pragma unroll
          for (int j = 0; j < 4; ++j)
            *(short8*)(dst + j*8) = *(const short8*)(srcp + j*8);
        }
      }
    }
    __syncthreads();
  }
}

// ---------------- fused node kernel, layers 1&2: one wave per node ----------------
// Counted-vmcnt asm pipeline (T4): all in-loop vmem is inline asm; waits never
// drain to 0 in steady state; 5-9 loads stay in flight per wave.
// Queue invariant at loop top: [S(g+1), A0..A3(g)] -> vmcnt(4) frees S only.
__global__ __launch_bounds__(256) void k_attn(const unsigned short* __restrict__ qb,
                                              const char* __restrict__ kvb,
                                              const unsigned short* __restrict__ xb,
                                              const int* __restrict__ rowptr,
                                              const int* __restrict__ degv,
                                              const int* __restrict__ srcs,
                                              const void* __restrict__ Wb,
                                              const void* __restrict__ lng,
                                              const void* __restrict__ lnb,
                                              unsigned short* __restrict__ hout,
                                              int N, int E, const int* __restrict__ flagp){
  int f32 = *flagp;
  int tid = threadIdx.x, w = tid >> 6, l = tid & 63;
  int n = blockIdx.x * 4 + w;
  if (n >= N) return;
  unsigned lof = (unsigned)l * 16u;
  size_t nbase = (size_t)n * 512;
  union KV { i32x4 v; _Float16 h[8]; half2v h2[4]; };
  half4 qv = *(const half4*)((const char*)qb + nbase + (unsigned)l * 8u);
  half2v q01 = { qv.x, qv.y }, q23 = { qv.z, qv.w };
  int e0 = rowptr[n]; if (e0 < 0) e0 = 0;
  int dg = degv[n]; if (dg < 0) dg = 0; if (dg > E) dg = E;
  const float scale = 0.17677669529663687f;  // 1/sqrt(32)
  float ss = 0.f, o0 = 0.f, o1 = 0.f, o2 = 0.f, o3 = 0.f;

  auto consume = [&](const i32x4& t, int valid){
    KV kv; kv.v = t;
    float p = dot4h(q01, q23, kv.h2[0], kv.h2[1]);
    p += __shfl_xor(p, 1); p += __shfl_xor(p, 2); p += __shfl_xor(p, 4);
    float a = valid ? __expf(lclamp(p * scale)) : 0.f;
    ss += a;
    o0 += a * (float)kv.h[4];
    o1 += a * (float)kv.h[5];
    o2 += a * (float)kv.h[6];
    o3 += a * (float)kv.h[7];
  };

  if (dg > 0){
    int ngr = ((dg + 3) & ~3) >> 2;   // 4-edge groups (padded CSR, srcs has +64 slack)
    unsigned sbyte = (unsigned)e0 * 4u;
    i32x4 sc, sn, a0, a1, a2, a3;
    asm volatile("global_load_dwordx4 %0, %1, %2" : "=v"(sc) : "v"(sbyte), "s"(srcs));
    asm volatile("s_waitcnt vmcnt(0)" : "+v"(sc));
    // issue next srcs BEFORE kv loads so it is oldest in queue
    asm volatile("global_load_dwordx4 %0, %1, %2" : "=v"(sn) : "v"(sbyte + 16u), "s"(srcs));
    asm volatile("global_load_dwordx4 %0, %1, %2" : "=v"(a0) : "v"((unsigned)sc[0] + lof), "s"(kvb));
    asm volatile("global_load_dwordx4 %0, %1, %2" : "=v"(a1) : "v"((unsigned)sc[1] + lof), "s"(kvb));
    asm volatile("global_load_dwordx4 %0, %1, %2" : "=v"(a2) : "v"((unsigned)sc[2] + lof), "s"(kvb));
    asm volatile("global_load_dwordx4 %0, %1, %2" : "=v"(a3) : "v"((unsigned)sc[3] + lof), "s"(kvb));
    int g = 0;
    #pragma unroll 1
    for (; g + 1 < ngr; ++g){
      asm volatile("s_waitcnt vmcnt(4)" : "+v"(sn));   // S(g+1) ready; A still in flight
      i32x4 offs = sn;
      i32x4 b0, b1, b2, b3;
      asm volatile("global_load_dwordx4 %0, %1, %2" : "=v"(sn) : "v"(sbyte + (unsigned)(g + 2) * 16u), "s"(srcs));
      asm volatile("global_load_dwordx4 %0, %1, %2" : "=v"(b0) : "v"((unsigned)offs[0] + lof), "s"(kvb));
      asm volatile("global_load_dwordx4 %0, %1, %2" : "=v"(b1) : "v"((unsigned)offs[1] + lof), "s"(kvb));
      asm volatile("global_load_dwordx4 %0, %1, %2" : "=v"(b2) : "v"((unsigned)offs[2] + lof), "s"(kvb));
      asm volatile("global_load_dwordx4 %0, %1, %2" : "=v"(b3) : "v"((unsigned)offs[3] + lof), "s"(kvb));
      // queue: [A0..A3, S(g+2), B0..B3] (9) -> counted waits, never 0
      asm volatile("s_waitcnt vmcnt(8)" : "+v"(a0)); consume(a0, 1);
      asm volatile("s_waitcnt vmcnt(7)" : "+v"(a1)); consume(a1, 1);
      asm volatile("s_waitcnt vmcnt(6)" : "+v"(a2)); consume(a2, 1);
      asm volatile("s_waitcnt vmcnt(5)" : "+v"(a3)); consume(a3, 1);
      a0 = b0; a1 = b1; a2 = b2; a3 = b3;
    }
    // epilogue: queue [S(junk), A0..A3]
    int b4 = g * 4;
    asm volatile("s_waitcnt vmcnt(3)" : "+v"(a0)); consume(a0, 1);
    asm volatile("s_waitcnt vmcnt(2)" : "+v"(a1)); consume(a1, b4 + 1 < dg);
    asm volatile("s_waitcnt vmcnt(1)" : "+v"(a2)); consume(a2, b4 + 2 < dg);
    asm volatile("s_waitcnt vmcnt(0)" : "+v"(a3)); consume(a3, b4 + 3 < dg);
  }

  float sinv = 1.f / (ss + 1e-16f);
  o0 = sane(o0 * sinv); o1 = sane(o1 * sinv);
  o2 = sane(o2 * sinv); o3 = sane(o3 * sinv);
  int c = l * 4;
  half4 xv = *(const half4*)((const char*)xb + nbase + (unsigned)l * 8u);
  float x0 = sane((float)xv.x), x1 = sane((float)xv.y);
  float x2 = sane((float)xv.z), x3 = sane((float)xv.w);
  float d = o0*ldin(Wb, c+0, f32) + x0*ldin(Wb, 256+c+0, f32) + (o0-x0)*ldin(Wb, 512+c+0, f32)
          + o1*ldin(Wb, c+1, f32) + x1*ldin(Wb, 256+c+1, f32) + (o1-x1)*ldin(Wb, 512+c+1, f32)
          + o2*ldin(Wb, c+2, f32) + x2*ldin(Wb, 256+c+2, f32) + (o2-x2)*ldin(Wb, 512+c+2, f32)
          + o3*ldin(Wb, c+3, f32) + x3*ldin(Wb, 256+c+3, f32) + (o3-x3)*ldin(Wb, 512+c+3, f32);
  #pragma unroll
  for (int off = 32; off; off >>= 1) d += __shfl_xor(d, off);
  float beta = 1.f / (1.f + __expf(-d));
  float r0 = beta*x0 + (1.f-beta)*o0;
  float r1 = beta*x1 + (1.f-beta)*o1;
  float r2 = beta*x2 + (1.f-beta)*o2;
  float r3 = beta*x3 + (1.f-beta)*o3;
  float sm = r0 + r1 + r2 + r3;
  #pragma unroll
  for (int off = 32; off; off >>= 1) sm += __shfl_xor(sm, off);
  float mu = sm * (1.f/256.f);
  float d0 = r0-mu, d1 = r1-mu, d2 = r2-mu, d3 = r3-mu;
  float vv2 = d0*d0 + d1*d1 + d2*d2 + d3*d3;
  #pragma unroll
  for (int off = 32; off; off >>= 1) vv2 += __shfl_xor(vv2, off);
  float rs = rsqrtf(vv2 * (1.f/256.f) + 1e-5f);
  us4 outv;
  outv.x = f2b(fmaxf(d0*rs*ldin(lng,c+0,f32) + ldin(lnb,c+0,f32), 0.f));
  outv.y = f2b(fmaxf(d1*rs*ldin(lng,c+1,f32) + ldin(lnb,c+1,f32), 0.f));
  outv.z = f2b(fmaxf(d2*rs*ldin(lng,c+2,f32) + ldin(lnb,c+2,f32), 0.f));
  outv.w = f2b(fmaxf(d3*rs*ldin(lng,c+3,f32) + ldin(lnb,c+3,f32), 0.f));
  *(us4*)&hout[(size_t)n * 256 + c] = outv;
}

// ---------------- fused node kernel, layer 3: one wave per node ----------------
// kv3 rows are 256 B interleaved (srcs>>2). 4 edge-slices x 16 lanes, depth-2 pipelined.
__global__ __launch_bounds__(256) void k_final(const unsigned short* __restrict__ q3b,
                                               const char* __restrict__ kv3b,
                                               const unsigned short* __restrict__ x3b,
                                               const int* __restrict__ rowptr,
                                               const int* __restrict__ degv,
                                               const int* __restrict__ srcs,
                                               const void* __restrict__ Wb,
                                               void* __restrict__ outp,
                                               int N, int E, const int* __restrict__ flagp){
  int f32 = *flagp;
  int tid = threadIdx.x, w = tid >> 6, l = tid & 63;
  int n = blockIdx.x * 4 + w;
  if (n >= N) return;
  int es = l >> 4, g = l & 15, j = g & 1;
  unsigned lof = (unsigned)g * 16u;
  size_t nbase = (size_t)n * 128;
  union KV { i32x4 v; _Float16 h[8]; half2v h2[4]; };
  half4 qv = *(const half4*)((const char*)q3b + nbase + (unsigned)g * 8u);
  half2v q01 = { qv.x, qv.y }, q23 = { qv.z, qv.w };
  int e0 = rowptr[n]; if (e0 < 0) e0 = 0;
  int dg = degv[n]; if (dg < 0) dg = 0; if (dg > E) dg = E;
  int npad = (dg + 3) & ~3;
  const float scale = 0.35355339059327373f;  // 1/sqrt(8)
  float ss = 0.f, o0 = 0.f, o1 = 0.f, o2 = 0.f, o3 = 0.f;

  auto consume = [&](const KV& kv, int valid){
    float p = dot4h(q01, q23, kv.h2[0], kv.h2[1]);
    p += __shfl_xor(p, 1);
    float a = valid ? __expf(lclamp(p * scale)) : 0.f;
    ss += a;
    o0 += a * (float)kv.h[4];
    o1 += a * (float)kv.h[5];
    o2 += a * (float)kv.h[6];
    o3 += a * (float)kv.h[7];
  };

  int idx = es;
  if (idx < npad){
    KV c;
    c.v = *(const i32x4*)(kv3b + (((unsigned)srcs[e0 + idx]) >> 2) + lof);
    #pragma unroll 1
    for (; idx + 4 < npad; idx += 4){
      KV nx;
      nx.v = *(const i32x4*)(kv3b + (((unsigned)srcs[e0 + idx + 4]) >> 2) + lof);
      consume(c, idx < dg);
      c = nx;
    }
    consume(c, idx < dg);
  }
  #pragma unroll
  for (int off = 16; off <= 32; off <<= 1){
    ss += __shfl_xor(ss, off);
    o0 += __shfl_xor(o0, off); o1 += __shfl_xor(o1, off);
    o2 += __shfl_xor(o2, off); o3 += __shfl_xor(o3, off);
  }
  float sinv = 1.f / (ss + 1e-16f);
  o0 = sane(o0 * sinv); o1 = sane(o1 * sinv);
  o2 = sane(o2 * sinv); o3 = sane(o3 * sinv);
  #pragma unroll
  for (int off = 2; off <= 8; off <<= 1){
    o0 += __shfl_xor(o0, off); o1 += __shfl_xor(o1, off);
    o2 += __shfl_xor(o2, off); o3 += __shfl_xor(o3, off);
  }
  o0 *= 0.125f; o1 *= 0.125f; o2 *= 0.125f; o3 *= 0.125f;
  half4 xv = *(const half4*)((const char*)x3b + nbase + (unsigned)(j * 8));
  float x0 = sane((float)xv.x), x1 = sane((float)xv.y);
  float x2 = sane((float)xv.z), x3v = sane((float)xv.w);
  int c = j*4;
  float d = o0*ldin(Wb, c+0, f32) + x0*ldin(Wb, 8+c+0, f32) + (o0-x0)*ldin(Wb, 16+c+0, f32)
          + o1*ldin(Wb, c+1, f32) + x1*ldin(Wb, 8+c+1, f32) + (o1-x1)*ldin(Wb, 16+c+1, f32)
          + o2*ldin(Wb, c+2, f32) + x2*ldin(Wb, 8+c+2, f32) + (o2-x2)*ldin(Wb, 16+c+2, f32)
          + o3*ldin(Wb, c+3, f32) + x3v*ldin(Wb, 8+c+3, f32) + (o3-x3v)*ldin(Wb, 16+c+3, f32);
  d += __shfl_xor(d, 1);
  float beta = 1.f / (1.f + __expf(-d));
  float r0 = beta*x0  + (1.f-beta)*o0;
  float r1 = beta*x1  + (1.f-beta)*o1;
  float r2 = beta*x2  + (1.f-beta)*o2;
  float r3 = beta*x3v + (1.f-beta)*o3;
  if (l < 2){
    if (f32){
      float* op = (float*)outp + (size_t)n*8 + l*4;
      op[0] = r0; op[1] = r1; op[2] = r2; op[3] = r3;
    } else {
      unsigned short* op = (unsigned short*)outp + (size_t)n*8 + l*4;
      op[0] = f2b(r0); op[1] = f2b(r1); op[2] = f2b(r2); op[3] = f2b(r3);
    }
  }
}

extern "C" void kernel_launch(void* const* d_in, const int* in_sizes, int n_in,
                              void* d_out, int out_size, void* d_ws, size_t ws_size,
                              hipStream_t stream){
  const int* ei = (const int*)d_in[1];
  const int N = in_sizes[0] / 256;
  const int E = in_sizes[1] / 2;
  const int Epad = E + 4 * N + 64;   // padded CSR capacity

  char* wsp = (char*)d_ws;
  size_t off = 0;
  auto alloc = [&](size_t b) -> void* {
    void* p = wsp + off; off = (off + b + 255) & ~(size_t)255; return p;
  };
  unsigned short* WT1  = (unsigned short*)alloc((size_t)1024*256*2);
  unsigned short* WT2  = (unsigned short*)alloc((size_t)1024*256*2);
  unsigned short* WT3  = (unsigned short*)alloc((size_t)256*256*2);
  float* bias1 = (float*)alloc(1024*4);
  float* bias2 = (float*)alloc(1024*4);
  float* bias3 = (float*)alloc(256*4);
  int* flag   = (int*)alloc(256);
  int* deg    = (int*)alloc((size_t)N*4);
  int* rowptr = (int*)alloc((size_t)(N+1)*4);
  int* cursor = (int*)alloc((size_t)N*4);
  int* bsum   = (int*)alloc(1024*4);
  int* boff   = (int*)alloc(1024*4);
  int* srcs   = (int*)alloc((size_t)Epad*4);
  unsigned short* xbf = (unsigned short*)alloc((size_t)N*256*2);
  unsigned short* qb  = (unsigned short*)alloc((size_t)N*256*2);
  char*           kvb = (char*)alloc((size_t)N*1024);
  unsigned short* xb  = (unsigned short*)alloc((size_t)N*256*2);
  unsigned short* hbuf= (unsigned short*)alloc((size_t)N*256*2);
  (void)ws_size; (void)n_in; (void)out_size;

  // dtype flag + canonical bf16 x
  k_flag<<<1, 256, 0, stream>>>((const unsigned short*)d_in[0], flag);
  int n4 = (N * 256) / 4;
  k_cvt<<<(n4 + 255) / 256, 256, 0, stream>>>(d_in[0], xbf, n4, flag);

  // CSR build (dst-sorted, 4-aligned padded segments), parallel scan
  hipMemsetAsync(deg, 0, (size_t)N*4, stream);
  hipMemsetAsync(srcs, 0, (size_t)Epad*4, stream);   // pad slots -> node 0 (masked later)
  int eb = (E + 255) / 256;
  int nbk = (N + 1023) / 1024;
  k_deg<<<eb, 256, 0, stream>>>(ei, E, N, deg);
  k_bsum<<<nbk, 256, 0, stream>>>(deg, N, bsum);
  k_bscan<<<1, 64, 0, stream>>>(bsum, nbk, boff, rowptr, N);
  k_rowptr<<<nbk, 256, 0, stream>>>(deg, boff, N, rowptr, cursor);
  k_scatter<<<eb, 256, 0, stream>>>(ei, E, N, Epad, cursor, srcs);

  // pack transposed fused weights + biases
  k_pack<<<1024, 256, 0, stream>>>(d_in[2],  d_in[3],  d_in[4],  d_in[5],  d_in[6],  d_in[7],  d_in[8],  d_in[9],  WT1, bias1, 256, 256, 256, flag);
  k_pack<<<1024, 256, 0, stream>>>(d_in[11], d_in[12], d_in[13], d_in[14], d_in[15], d_in[16], d_in[17], d_in[18], WT2, bias2, 256, 256, 256, flag);
  k_pack<<< 256, 256, 0, stream>>>(d_in[20], d_in[21], d_in[22], d_in[23], d_in[24], d_in[25], d_in[26], d_in[27], WT3, bias3,  64,   8, 256, flag);

  int rb = (N + 63) / 64;
  int nb = (N + 3) / 4;
  // layer 1
  k_gemm<<<rb * 4, 256, 0, stream>>>(xbf, WT1, bias1, qb, kvb, xb, N, 1024, 8);
  k_attn<<<nb, 256, 0, stream>>>(qb, kvb, xb, rowptr, deg, srcs, d_in[10], d_in[29], d_in[30], hbuf, N, E, flag);
  // layer 2
  k_gemm<<<rb * 4, 256, 0, stream>>>(hbuf, WT2, bias2, qb, kvb, xb, N, 1024, 8);
  k_attn<<<nb, 256, 0, stream>>>(qb, kvb, xb, rowptr, deg, srcs, d_in[19], d_in[31], d_in[32], hbuf, N, E, flag);
  // layer 3
  k_gemm<<<rb, 256, 0, stream>>>(hbuf, WT3, bias3, qb, kvb, xb, N, 256, 6);
  k_final<<<nb, 256, 0, stream>>>(qb, kvb, xb, rowptr, deg, srcs, d_in[28], d_out, N, E, flag);
}

// Round 11
// 593.999 us; speedup vs baseline: 1.0086x; 1.0086x over previous
//
#include <hip/hip_runtime.h>
#include <stdint.h>

typedef __attribute__((ext_vector_type(8))) short short8;
typedef __attribute__((ext_vector_type(4))) float f32x4;
typedef __attribute__((ext_vector_type(4))) _Float16 half4;
typedef __attribute__((ext_vector_type(2))) _Float16 half2v;
typedef __attribute__((ext_vector_type(4))) int i32x4;

struct us4 { unsigned short x, y, z, w; };

__device__ __forceinline__ float b2f(unsigned short u){
  union { unsigned int i; float f; } x; x.i = ((unsigned int)u) << 16; return x.f;
}
__device__ __forceinline__ unsigned short f2b(float f){
  union { float f; unsigned int i; } x; x.f = f;
  unsigned int i = x.i;
  unsigned int r = (i + 0x7FFFu + ((i >> 16) & 1u)) >> 16;
  return (unsigned short)r;
}
__device__ __forceinline__ unsigned short f2h(float f){
  _Float16 h = (_Float16)f;
  union { _Float16 h; unsigned short u; } c; c.h = h; return c.u;
}
__device__ __forceinline__ float sane(float v){
  return fminf(fmaxf(v, -1e30f), 1e30f);
}
// clamp logit: NaN -> -60, range +-60 (exp-safe; softmax invariant to shift)
__device__ __forceinline__ float lclamp(float v){
  return fminf(fmaxf(v, -60.f), 60.f);
}
__device__ __forceinline__ float ldin(const void* p, size_t i, int f32){
  return f32 ? ((const float*)p)[i] : b2f(((const unsigned short*)p)[i]);
}
__device__ __forceinline__ float dot4h(half2v a0, half2v a1, half2v b0, half2v b1){
#if __has_builtin(__builtin_amdgcn_fdot2)
  return __builtin_amdgcn_fdot2(a0, b0, __builtin_amdgcn_fdot2(a1, b1, 0.f, false), false);
#else
  return (float)a0.x*(float)b0.x + (float)a0.y*(float)b0.y
       + (float)a1.x*(float)b1.x + (float)a1.y*(float)b1.y;
#endif
}
// async global->LDS, 16B per lane; lds dest = wave-uniform base + lane*16
__device__ __forceinline__ void gload_lds16(const void* g, void* l){
  __builtin_amdgcn_global_load_lds(
      (const __attribute__((address_space(1))) void*)g,
      (__attribute__((address_space(3))) void*)l, 16, 0, 0);
}

// ---------------- dtype discriminator ----------------
__global__ void k_flag(const unsigned short* __restrict__ xu, int* __restrict__ flag){
  __shared__ int cnt;
  if (threadIdx.x == 0) cnt = 0;
  __syncthreads();
  unsigned u = xu[2 * threadIdx.x];
  int e = (u >> 7) & 0xFF;
  if (e >= 97 && e <= 132) atomicAdd(&cnt, 1);
  __syncthreads();
  if (threadIdx.x == 0) flag[0] = (cnt >= 192) ? 0 : 1;   // 0=bf16, 1=fp32
}

// ---------------- x -> bf16 canonical copy (vectorized) ----------------
__global__ void k_cvt(const void* __restrict__ xin, unsigned short* __restrict__ xb,
                      int n4, const int* __restrict__ flagp){
  int f32 = *flagp;
  int i = blockIdx.x * 256 + threadIdx.x;
  if (i < n4){
    if (f32){
      float4 v = ((const float4*)xin)[i];
      us4 o = { f2b(v.x), f2b(v.y), f2b(v.z), f2b(v.w) };
      ((us4*)xb)[i] = o;
    } else {
      ((us4*)xb)[i] = ((const us4*)xin)[i];
    }
  }
}

// ---------------- CSR build (parallel scan), 4-aligned padded segments ----------------
__global__ void k_deg(const int* __restrict__ ei, int E, int N, int* __restrict__ deg){
  int e = blockIdx.x * 256 + threadIdx.x;
  if (e < E){
    unsigned d = (unsigned)ei[E + e];
    if (d < (unsigned)N) atomicAdd(&deg[d], 1);
  }
}

__device__ __forceinline__ int pad4(int d){ return (d + 3) & ~3; }

// block b sums padded deg[b*1024 .. +1023] -> bsum[b]   (256 threads)
__global__ void k_bsum(const int* __restrict__ deg, int N, int* __restrict__ bsum){
  int b = blockIdx.x, t = threadIdx.x;
  int i0 = b * 1024 + t * 4;
  int s = 0;
  if (i0 + 4 <= N){
    int4 v = *(const int4*)&deg[i0];
    s = pad4(v.x) + pad4(v.y) + pad4(v.z) + pad4(v.w);
  } else {
    #pragma unroll
    for (int j = 0; j < 4; ++j){ int i = i0 + j; if (i < N) s += pad4(deg[i]); }
  }
  #pragma unroll
  for (int off = 32; off; off >>= 1) s += __shfl_xor(s, off);
  __shared__ int ws[4];
  if ((t & 63) == 0) ws[t >> 6] = s;
  __syncthreads();
  if (t == 0) bsum[b] = ws[0] + ws[1] + ws[2] + ws[3];
}

// one wave: exclusive scan of nb block sums -> boff; rowptr[N] = total   (64 threads)
__global__ void k_bscan(const int* __restrict__ bsum, int nb,
                        int* __restrict__ boff, int* __restrict__ rowptr, int N){
  int t = threadIdx.x;
  if (nb <= 64){
    int v = (t < nb) ? bsum[t] : 0;
    int inc = v;
    #pragma unroll
    for (int off = 1; off < 64; off <<= 1){
      int u = __shfl_up(inc, off);
      if (t >= off) inc += u;
    }
    if (t < nb) boff[t] = inc - v;
    if (t == 63) rowptr[N] = inc;   // lane 63 holds grand total (padded)
  } else {
    if (t == 0){
      int run = 0;
      for (int i = 0; i < nb; ++i){ boff[i] = run; run += bsum[i]; }
      rowptr[N] = run;
    }
  }
}

// block b: intra-block exclusive scan of padded deg; write rowptr (padded starts) + cursor
__global__ void k_rowptr(const int* __restrict__ deg, const int* __restrict__ boff,
                         int N, int* __restrict__ rowptr, int* __restrict__ cursor){
  int b = blockIdx.x, t = threadIdx.x;
  int i0 = b * 1024 + t * 4;
  int d0 = 0, d1 = 0, d2 = 0, d3 = 0;
  if (i0 + 4 <= N){
    int4 v = *(const int4*)&deg[i0];
    d0 = v.x; d1 = v.y; d2 = v.z; d3 = v.w;
  } else {
    if (i0     < N) d0 = deg[i0];
    if (i0 + 1 < N) d1 = deg[i0 + 1];
    if (i0 + 2 < N) d2 = deg[i0 + 2];
    if (i0 + 3 < N) d3 = deg[i0 + 3];
  }
  int p0 = pad4(d0), p1 = pad4(d1), p2 = pad4(d2), p3 = pad4(d3);
  int s = p0 + p1 + p2 + p3;
  int lane = t & 63, w = t >> 6;
  int inc = s;
  #pragma unroll
  for (int off = 1; off < 64; off <<= 1){
    int u = __shfl_up(inc, off);
    if (lane >= off) inc += u;
  }
  int wex = inc - s;   // wave-exclusive prefix
  __shared__ int wtot[4];
  if (lane == 63) wtot[w] = inc;
  __syncthreads();
  int cross = 0;
  for (int i = 0; i < w; ++i) cross += wtot[i];
  int basev = boff[b] + cross + wex;
  int r0 = basev, r1 = basev + p0, r2 = r1 + p1, r3 = r2 + p2;
  if (i0 + 4 <= N){
    int4 o = { r0, r1, r2, r3 };
    *(int4*)&rowptr[i0] = o;
    *(int4*)&cursor[i0] = o;
  } else {
    if (i0     < N){ rowptr[i0]   = r0; cursor[i0]   = r0; }
    if (i0 + 1 < N){ rowptr[i0+1] = r1; cursor[i0+1] = r1; }
    if (i0 + 2 < N){ rowptr[i0+2] = r2; cursor[i0+2] = r2; }
    if (i0 + 3 < N){ rowptr[i0+3] = r3; cursor[i0+3] = r3; }
  }
}

// srcs[] stores BYTE offsets into the interleaved kv buffer (s*1024), clamped here.
__global__ void k_scatter(const int* __restrict__ ei, int E, int N, int Epad,
                          int* __restrict__ cursor, int* __restrict__ srcs){
  int e = blockIdx.x * 256 + threadIdx.x;
  if (e < E){
    unsigned d = (unsigned)ei[E + e];
    if (d < (unsigned)N){
      int pos = atomicAdd(&cursor[d], 1);
      if ((unsigned)pos < (unsigned)Epad){
        unsigned s = (unsigned)ei[e];
        srcs[pos] = (s < (unsigned)N) ? (int)(s * 1024u) : 0;
      }
    }
  }
}

// ---------------- weight pack: WT[cg][k] = W_mat[k][c] (bf16), bias as float ----------------
__global__ void k_pack(const void* __restrict__ Wq, const void* __restrict__ bq,
                       const void* __restrict__ Wk, const void* __restrict__ bk,
                       const void* __restrict__ Wv, const void* __restrict__ bv,
                       const void* __restrict__ Ws, const void* __restrict__ bs,
                       unsigned short* __restrict__ WT, float* __restrict__ bias,
                       int Mq, int Ms, int K, const int* __restrict__ flagp){
  int f32 = *flagp;
  int cg = blockIdx.x;
  int k  = threadIdx.x;
  int mat, c, mc;
  if (cg < 3 * Mq){ mat = cg / Mq; c = cg % Mq; mc = Mq; }
  else if (cg < 3 * Mq + Ms){ mat = 3; c = cg - 3 * Mq; mc = Ms; }
  else { mat = 4; c = 0; mc = 1; }
  const void* W = (mat==0)?Wq:(mat==1)?Wk:(mat==2)?Wv:(mat==3)?Ws:(const void*)0;
  WT[(size_t)cg * K + k] = (mat < 4) ? f2b(ldin(W, (size_t)k * mc + c, f32)) : (unsigned short)0;
  if (k == 0){
    const void* B = (mat==0)?bq:(mat==1)?bk:(mat==2)?bv:(mat==3)?bs:(const void*)0;
    bias[cg] = (mat < 4) ? ldin(B, c, f32) : 0.f;
  }
}

// ---------------- GEMM: 64-row x 256-col tile per block (split grid),
// T3 2-phase double-buffered global_load_lds: stage(t+1) issued BEFORE compute(t),
// one barrier per K-step (9 total vs 16). LDS 2x20.5KB; Clds overlays buf0.
// Layers 1/2 (Mout=1024): grid = rb*4; it = bid%4:
//   it0: q blks 0-3 | it1: k0,k1,v0,v1 | it2: k2,k3,v2,v3 | it3: x blks 0-3
// Layer 3 (Mout=256): grid = rb; single iteration = q,k,v,x across waves.
__global__ __launch_bounds__(256) void k_gemm(const unsigned short* __restrict__ A,
                                              const unsigned short* __restrict__ WT,
                                              const float* __restrict__ bias,
                                              unsigned short* __restrict__ qout,
                                              char* __restrict__ kvout,
                                              unsigned short* __restrict__ xout,
                                              int N, int Mout, int secshift){
  constexpr int BUF = 64*32 + 256*32;   // shorts per buffer (A-chunk + B-chunk)
  __shared__ __align__(16) unsigned short sh[2*BUF];
  auto Clds = (unsigned short(*)[276])sh;   // overlay after K-loop (17.7KB < BUF*2)
  int tid = threadIdx.x, wid = tid >> 6, lane = tid & 63;
  int l15 = lane & 15, l4 = lane >> 4;
  int nit = Mout >> 8;   // 4 (layers 1/2) or 1 (layer 3)
  int it = blockIdx.x % nit;
  int row0 = (blockIdx.x / nit) * 64;
  int secw = 1 << secshift;
  int sec, blk;
  if (nit == 1){ sec = wid; blk = 0; }
  else if (it == 0){ sec = 0; blk = wid; }
  else if (it == 3){ sec = 3; blk = wid; }
  else { sec = (wid < 2) ? 1 : 2; blk = (it - 1) * 2 + (wid & 1); }
  int cbf = sec * secw + blk * 64;

  // per-lane staging sources (advance by k0 each step)
  int sr = lane >> 2, sc = lane & 3;   // 16 rows x 4 chunks(16B) per wave-call
  int arow = row0 + wid * 16 + sr; if (arow >= N) arow = N - 1;
  const unsigned short* Ag = A + (size_t)arow * 256 + sc * 8;
  const unsigned short* Bg[4];
  #pragma unroll
  for (int j = 0; j < 4; ++j){
    int r = wid * 64 + j * 16 + sr;   // block-col this lane stages
    int gcol;
    if (nit == 1 || it == 0) gcol = r;
    else if (it == 3)        gcol = 768 + r;
    else if (it == 1)        gcol = r + (r < 128 ? 256 : 384);
    else                     gcol = r + (r < 128 ? 384 : 512);
    Bg[j] = WT + (size_t)gcol * 256 + sc * 8;
  }
  int aoff = (wid * 16) * 32;          // wave-uniform dest offsets within a buffer
  int boff2 = 64*32 + (wid * 64) * 32;

  // prologue: stage step 0 into buffer 0
  gload_lds16(Ag, sh + aoff);
  gload_lds16(Bg[0], sh + boff2);
  gload_lds16(Bg[1], sh + boff2 + 16*32);
  gload_lds16(Bg[2], sh + boff2 + 32*32);
  gload_lds16(Bg[3], sh + boff2 + 48*32);
  __syncthreads();

  f32x4 acc[4][4] = {};
  #pragma unroll
  for (int t = 0; t < 8; ++t){
    int cur = t & 1;
    const unsigned short* Ab = sh + cur*BUF;
    const unsigned short* Bb = sh + cur*BUF + 64*32;
    if (t < 7){
      int k0n = (t + 1) * 32;
      unsigned short* Ad = sh + (cur^1)*BUF + aoff;
      unsigned short* Bd = sh + (cur^1)*BUF + boff2;
      gload_lds16(Ag + k0n, Ad);
      gload_lds16(Bg[0] + k0n, Bd);
      gload_lds16(Bg[1] + k0n, Bd + 16*32);
      gload_lds16(Bg[2] + k0n, Bd + 32*32);
      gload_lds16(Bg[3] + k0n, Bd + 48*32);
    }
    short8 a0 = *(const short8*)&Ab[(     l15)*32 + l4*8];
    short8 a1 = *(const short8*)&Ab[(16 + l15)*32 + l4*8];
    short8 a2 = *(const short8*)&Ab[(32 + l15)*32 + l4*8];
    short8 a3 = *(const short8*)&Ab[(48 + l15)*32 + l4*8];
    short8 b0 = *(const short8*)&Bb[(wid*64      + l15)*32 + l4*8];
    short8 b1 = *(const short8*)&Bb[(wid*64 + 16 + l15)*32 + l4*8];
    short8 b2 = *(const short8*)&Bb[(wid*64 + 32 + l15)*32 + l4*8];
    short8 b3 = *(const short8*)&Bb[(wid*64 + 48 + l15)*32 + l4*8];
    acc[0][0] = __builtin_amdgcn_mfma_f32_16x16x32_bf16(a0, b0, acc[0][0], 0,0,0);
    acc[0][1] = __builtin_amdgcn_mfma_f32_16x16x32_bf16(a0, b1, acc[0][1], 0,0,0);
    acc[0][2] = __builtin_amdgcn_mfma_f32_16x16x32_bf16(a0, b2, acc[0][2], 0,0,0);
    acc[0][3] = __builtin_amdgcn_mfma_f32_16x16x32_bf16(a0, b3, acc[0][3], 0,0,0);
    acc[1][0] = __builtin_amdgcn_mfma_f32_16x16x32_bf16(a1, b0, acc[1][0], 0,0,0);
    acc[1][1] = __builtin_amdgcn_mfma_f32_16x16x32_bf16(a1, b1, acc[1][1], 0,0,0);
    acc[1][2] = __builtin_amdgcn_mfma_f32_16x16x32_bf16(a1, b2, acc[1][2], 0,0,0);
    acc[1][3] = __builtin_amdgcn_mfma_f32_16x16x32_bf16(a1, b3, acc[1][3], 0,0,0);
    acc[2][0] = __builtin_amdgcn_mfma_f32_16x16x32_bf16(a2, b0, acc[2][0], 0,0,0);
    acc[2][1] = __builtin_amdgcn_mfma_f32_16x16x32_bf16(a2, b1, acc[2][1], 0,0,0);
    acc[2][2] = __builtin_amdgcn_mfma_f32_16x16x32_bf16(a2, b2, acc[2][2], 0,0,0);
    acc[2][3] = __builtin_amdgcn_mfma_f32_16x16x32_bf16(a2, b3, acc[2][3], 0,0,0);
    acc[3][0] = __builtin_amdgcn_mfma_f32_16x16x32_bf16(a3, b0, acc[3][0], 0,0,0);
    acc[3][1] = __builtin_amdgcn_mfma_f32_16x16x32_bf16(a3, b1, acc[3][1], 0,0,0);
    acc[3][2] = __builtin_amdgcn_mfma_f32_16x16x32_bf16(a3, b2, acc[3][2], 0,0,0);
    acc[3][3] = __builtin_amdgcn_mfma_f32_16x16x32_bf16(a3, b3, acc[3][3], 0,0,0);
    __syncthreads();   // drains next stage (overlapped with the MFMAs above) + read-done
  }
  int strow = tid >> 3, stchunk = tid & 7;
  #pragma unroll
  for (int ph = 0; ph < 2; ++ph){
    #pragma unroll
    for (int rt2 = 0; rt2 < 2; ++rt2){
      int rt = ph*2 + rt2;
      #pragma unroll
      for (int ct = 0; ct < 4; ++ct){
        float bv = bias[cbf + ct*16 + l15];
        #pragma unroll
        for (int r = 0; r < 4; ++r)
          Clds[rt2*16 + l4*4 + r][wid*64 + ct*16 + l15] = f2h(acc[rt][ct][r] + bv);
      }
    }
    __syncthreads();
    int grow = row0 + ph*32 + strow;
    if (grow < N){
      if (nit == 4){
        if (it == 0 || it == 3){
          unsigned short* Bp = (it == 0) ? qout : xout;
          int g0 = stchunk * 32;
          unsigned short* dst = Bp + (size_t)grow * secw + g0;
          const unsigned short* srcp = &Clds[strow][g0];
          #pragma unroll
          for (int j = 0; j < 4; ++j)
            *(short8*)(dst + j*8) = *(const short8*)(srcp + j*8);
        } else {
          int secbase = (it == 1) ? 0 : 128;
          int scl = stchunk * 16;
          char* dstb = kvout + (size_t)grow * 1024 + (size_t)(secbase + scl) * 4;
          const unsigned short* kp = &Clds[strow][scl];
          const unsigned short* vp = &Clds[strow][128 + scl];
          #pragma unroll
          for (int g2 = 0; g2 < 4; ++g2){
            union { unsigned long long u[2]; i32x4 v; } st;
            st.u[0] = *(const unsigned long long*)(kp + g2*4);
            st.u[1] = *(const unsigned long long*)(vp + g2*4);
            *(i32x4*)(dstb + g2*16) = st.v;
          }
        }
      } else {
        // layer 3: q | kv | x mixed in one iteration
        if (stchunk < 2){
          int g0 = stchunk * 32;
          unsigned short* dst = qout + (size_t)grow * secw + g0;
          const unsigned short* srcp = &Clds[strow][g0];
          #pragma unroll
          for (int j = 0; j < 4; ++j)
            *(short8*)(dst + j*8) = *(const short8*)(srcp + j*8);
        } else if (stchunk < 6){
          int scl = (stchunk - 2) * 16;
          char* dstb = kvout + (size_t)grow * 256 + (size_t)scl * 4;
          const unsigned short* kp = &Clds[strow][64 + scl];
          const unsigned short* vp = &Clds[strow][128 + scl];
          #pragma unroll
          for (int g2 = 0; g2 < 4; ++g2){
            union { unsigned long long u[2]; i32x4 v; } st;
            st.u[0] = *(const unsigned long long*)(kp + g2*4);
            st.u[1] = *(const unsigned long long*)(vp + g2*4);
            *(i32x4*)(dstb + g2*16) = st.v;
          }
        } else {
          int g0 = (stchunk - 6) * 32;
          unsigned short* dst = xout + (size_t)grow * secw + g0;
          const unsigned short* srcp = &Clds[strow][192 + g0];
          #pragma unroll
          for (int j = 0; j < 4; ++j)
            *(short8*)(dst + j*8) = *(const short8*)(srcp + j*8);
        }
      }
    }
    __syncthreads();
  }
}

// ---------------- fused node kernel, layers 1&2: one wave per node ----------------
// One 16B gather per edge (interleaved kv). Depth-2 pipelined groups of 4 edges.
// At the delivered-bandwidth roofline (~6 TB/s incl. cache hits) — do not touch.
__global__ __launch_bounds__(256) void k_attn(const unsigned short* __restrict__ qb,
                                              const char* __restrict__ kvb,
                                              const unsigned short* __restrict__ xb,
                                              const int* __restrict__ rowptr,
                                              const int* __restrict__ degv,
                                              const int* __restrict__ srcs,
                                              const void* __restrict__ Wb,
                                              const void* __restrict__ lng,
                                              const void* __restrict__ lnb,
                                              unsigned short* __restrict__ hout,
                                              int N, int E, const int* __restrict__ flagp){
  int f32 = *flagp;
  int tid = threadIdx.x, w = tid >> 6, l = tid & 63;
  int n = blockIdx.x * 4 + w;
  if (n >= N) return;
  unsigned lof = (unsigned)l * 16u;
  size_t nbase = (size_t)n * 512;
  union KV { i32x4 v; _Float16 h[8]; half2v h2[4]; };
  half4 qv = *(const half4*)((const char*)qb + nbase + (unsigned)l * 8u);
  half2v q01 = { qv.x, qv.y }, q23 = { qv.z, qv.w };
  int e0 = rowptr[n]; if (e0 < 0) e0 = 0;
  int dg = degv[n]; if (dg < 0) dg = 0; if (dg > E) dg = E;
  int npad = (dg + 3) & ~3;
  const float scale = 0.17677669529663687f;  // 1/sqrt(32)
  float ss = 0.f, o0 = 0.f, o1 = 0.f, o2 = 0.f, o3 = 0.f;

  auto consume = [&](const KV& kv, int valid){
    float p = dot4h(q01, q23, kv.h2[0], kv.h2[1]);
    p += __shfl_xor(p, 1); p += __shfl_xor(p, 2); p += __shfl_xor(p, 4);
    float a = valid ? __expf(lclamp(p * scale)) : 0.f;
    ss += a;
    o0 += a * (float)kv.h[4];
    o1 += a * (float)kv.h[5];
    o2 += a * (float)kv.h[6];
    o3 += a * (float)kv.h[7];
  };

  if (npad > 0){
    i32x4 offs = *(const i32x4*)&srcs[e0];   // e0 is 4-aligned (padded CSR)
    KV c0, c1, c2, c3;
    c0.v = *(const i32x4*)(kvb + (unsigned)offs[0] + lof);
    c1.v = *(const i32x4*)(kvb + (unsigned)offs[1] + lof);
    c2.v = *(const i32x4*)(kvb + (unsigned)offs[2] + lof);
    c3.v = *(const i32x4*)(kvb + (unsigned)offs[3] + lof);
    int base = 0;
    #pragma unroll 1
    for (; base + 4 < npad; base += 4){
      i32x4 offsN = *(const i32x4*)&srcs[e0 + base + 4];
      KV n0, n1, n2, n3;
      n0.v = *(const i32x4*)(kvb + (unsigned)offsN[0] + lof);
      n1.v = *(const i32x4*)(kvb + (unsigned)offsN[1] + lof);
      n2.v = *(const i32x4*)(kvb + (unsigned)offsN[2] + lof);
      n3.v = *(const i32x4*)(kvb + (unsigned)offsN[3] + lof);
      // in-loop groups are always fully valid (only the last group can be padded)
      consume(c0, 1); consume(c1, 1); consume(c2, 1); consume(c3, 1);
      c0 = n0; c1 = n1; c2 = n2; c3 = n3;
    }
    consume(c0, base + 0 < dg);
    consume(c1, base + 1 < dg);
    consume(c2, base + 2 < dg);
    consume(c3, base + 3 < dg);
  }

  float sinv = 1.f / (ss + 1e-16f);
  o0 = sane(o0 * sinv); o1 = sane(o1 * sinv);
  o2 = sane(o2 * sinv); o3 = sane(o3 * sinv);
  int c = l * 4;
  half4 xv = *(const half4*)((const char*)xb + nbase + (unsigned)l * 8u);
  float x0 = sane((float)xv.x), x1 = sane((float)xv.y);
  float x2 = sane((float)xv.z), x3 = sane((float)xv.w);
  float d = o0*ldin(Wb, c+0, f32) + x0*ldin(Wb, 256+c+0, f32) + (o0-x0)*ldin(Wb, 512+c+0, f32)
          + o1*ldin(Wb, c+1, f32) + x1*ldin(Wb, 256+c+1, f32) + (o1-x1)*ldin(Wb, 512+c+1, f32)
          + o2*ldin(Wb, c+2, f32) + x2*ldin(Wb, 256+c+2, f32) + (o2-x2)*ldin(Wb, 512+c+2, f32)
          + o3*ldin(Wb, c+3, f32) + x3*ldin(Wb, 256+c+3, f32) + (o3-x3)*ldin(Wb, 512+c+3, f32);
  #pragma unroll
  for (int off = 32; off; off >>= 1) d += __shfl_xor(d, off);
  float beta = 1.f / (1.f + __expf(-d));
  float r0 = beta*x0 + (1.f-beta)*o0;
  float r1 = beta*x1 + (1.f-beta)*o1;
  float r2 = beta*x2 + (1.f-beta)*o2;
  float r3 = beta*x3 + (1.f-beta)*o3;
  float sm = r0 + r1 + r2 + r3;
  #pragma unroll
  for (int off = 32; off; off >>= 1) sm += __shfl_xor(sm, off);
  float mu = sm * (1.f/256.f);
  float d0 = r0-mu, d1 = r1-mu, d2 = r2-mu, d3 = r3-mu;
  float vv2 = d0*d0 + d1*d1 + d2*d2 + d3*d3;
  #pragma unroll
  for (int off = 32; off; off >>= 1) vv2 += __shfl_xor(vv2, off);
  float rs = rsqrtf(vv2 * (1.f/256.f) + 1e-5f);
  us4 outv;
  outv.x = f2b(fmaxf(d0*rs*ldin(lng,c+0,f32) + ldin(lnb,c+0,f32), 0.f));
  outv.y = f2b(fmaxf(d1*rs*ldin(lng,c+1,f32) + ldin(lnb,c+1,f32), 0.f));
  outv.z = f2b(fmaxf(d2*rs*ldin(lng,c+2,f32) + ldin(lnb,c+2,f32), 0.f));
  outv.w = f2b(fmaxf(d3*rs*ldin(lng,c+3,f32) + ldin(lnb,c+3,f32), 0.f));
  *(us4*)&hout[(size_t)n * 256 + c] = outv;
}

// ---------------- fused node kernel, layer 3: one wave per node ----------------
// kv3 rows are 256 B interleaved (srcs>>2). 4 edge-slices x 16 lanes, depth-2 pipelined.
__global__ __launch_bounds__(256) void k_final(const unsigned short* __restrict__ q3b,
                                               const char* __restrict__ kv3b,
                                               const unsigned short* __restrict__ x3b,
                                               const int* __restrict__ rowptr,
                                               const int* __restrict__ degv,
                                               const int* __restrict__ srcs,
                                               const void* __restrict__ Wb,
                                               void* __restrict__ outp,
                                               int N, int E, const int* __restrict__ flagp){
  int f32 = *flagp;
  int tid = threadIdx.x, w = tid >> 6, l = tid & 63;
  int n = blockIdx.x * 4 + w;
  if (n >= N) return;
  int es = l >> 4, g = l & 15, j = g & 1;
  unsigned lof = (unsigned)g * 16u;
  size_t nbase = (size_t)n * 128;
  union KV { i32x4 v; _Float16 h[8]; half2v h2[4]; };
  half4 qv = *(const half4*)((const char*)q3b + nbase + (unsigned)g * 8u);
  half2v q01 = { qv.x, qv.y }, q23 = { qv.z, qv.w };
  int e0 = rowptr[n]; if (e0 < 0) e0 = 0;
  int dg = degv[n]; if (dg < 0) dg = 0; if (dg > E) dg = E;
  int npad = (dg + 3) & ~3;
  const float scale = 0.35355339059327373f;  // 1/sqrt(8)
  float ss = 0.f, o0 = 0.f, o1 = 0.f, o2 = 0.f, o3 = 0.f;

  auto consume = [&](const KV& kv, int valid){
    float p = dot4h(q01, q23, kv.h2[0], kv.h2[1]);
    p += __shfl_xor(p, 1);
    float a = valid ? __expf(lclamp(p * scale)) : 0.f;
    ss += a;
    o0 += a * (float)kv.h[4];
    o1 += a * (float)kv.h[5];
    o2 += a * (float)kv.h[6];
    o3 += a * (float)kv.h[7];
  };

  int idx = es;
  if (idx < npad){
    KV c;
    c.v = *(const i32x4*)(kv3b + (((unsigned)srcs[e0 + idx]) >> 2) + lof);
    #pragma unroll 1
    for (; idx + 4 < npad; idx += 4){
      KV nx;
      nx.v = *(const i32x4*)(kv3b + (((unsigned)srcs[e0 + idx + 4]) >> 2) + lof);
      consume(c, idx < dg);
      c = nx;
    }
    consume(c, idx < dg);
  }
  #pragma unroll
  for (int off = 16; off <= 32; off <<= 1){
    ss += __shfl_xor(ss, off);
    o0 += __shfl_xor(o0, off); o1 += __shfl_xor(o1, off);
    o2 += __shfl_xor(o2, off); o3 += __shfl_xor(o3, off);
  }
  float sinv = 1.f / (ss + 1e-16f);
  o0 = sane(o0 * sinv); o1 = sane(o1 * sinv);
  o2 = sane(o2 * sinv); o3 = sane(o3 * sinv);
  #pragma unroll
  for (int off = 2; off <= 8; off <<= 1){
    o0 += __shfl_xor(o0, off); o1 += __shfl_xor(o1, off);
    o2 += __shfl_xor(o2, off); o3 += __shfl_xor(o3, off);
  }
  o0 *= 0.125f; o1 *= 0.125f; o2 *= 0.125f; o3 *= 0.125f;
  half4 xv = *(const half4*)((const char*)x3b + nbase + (unsigned)(j * 8));
  float x0 = sane((float)xv.x), x1 = sane((float)xv.y);
  float x2 = sane((float)xv.z), x3v = sane((float)xv.w);
  int c = j*4;
  float d = o0*ldin(Wb, c+0, f32) + x0*ldin(Wb, 8+c+0, f32) + (o0-x0)*ldin(Wb, 16+c+0, f32)
          + o1*ldin(Wb, c+1, f32) + x1*ldin(Wb, 8+c+1, f32) + (o1-x1)*ldin(Wb, 16+c+1, f32)
          + o2*ldin(Wb, c+2, f32) + x2*ldin(Wb, 8+c+2, f32) + (o2-x2)*ldin(Wb, 16+c+2, f32)
          + o3*ldin(Wb, c+3, f32) + x3v*ldin(Wb, 8+c+3, f32) + (o3-x3v)*ldin(Wb, 16+c+3, f32);
  d += __shfl_xor(d, 1);
  float beta = 1.f / (1.f + __expf(-d));
  float r0 = beta*x0  + (1.f-beta)*o0;
  float r1 = beta*x1  + (1.f-beta)*o1;
  float r2 = beta*x2  + (1.f-beta)*o2;
  float r3 = beta*x3v + (1.f-beta)*o3;
  if (l < 2){
    if (f32){
      float* op = (float*)outp + (size_t)n*8 + l*4;
      op[0] = r0; op[1] = r1; op[2] = r2; op[3] = r3;
    } else {
      unsigned short* op = (unsigned short*)outp + (size_t)n*8 + l*4;
      op[0] = f2b(r0); op[1] = f2b(r1); op[2] = f2b(r2); op[3] = f2b(r3);
    }
  }
}

extern "C" void kernel_launch(void* const* d_in, const int* in_sizes, int n_in,
                              void* d_out, int out_size, void* d_ws, size_t ws_size,
                              hipStream_t stream){
  const int* ei = (const int*)d_in[1];
  const int N = in_sizes[0] / 256;
  const int E = in_sizes[1] / 2;
  const int Epad = E + 4 * N + 64;   // padded CSR capacity

  char* wsp = (char*)d_ws;
  size_t off = 0;
  auto alloc = [&](size_t b) -> void* {
    void* p = wsp + off; off = (off + b + 255) & ~(size_t)255; return p;
  };
  unsigned short* WT1  = (unsigned short*)alloc((size_t)1024*256*2);
  unsigned short* WT2  = (unsigned short*)alloc((size_t)1024*256*2);
  unsigned short* WT3  = (unsigned short*)alloc((size_t)256*256*2);
  float* bias1 = (float*)alloc(1024*4);
  float* bias2 = (float*)alloc(1024*4);
  float* bias3 = (float*)alloc(256*4);
  int* flag   = (int*)alloc(256);
  int* deg    = (int*)alloc((size_t)N*4);
  int* rowptr = (int*)alloc((size_t)(N+1)*4);
  int* cursor = (int*)alloc((size_t)N*4);
  int* bsum   = (int*)alloc(1024*4);
  int* boff   = (int*)alloc(1024*4);
  int* srcs   = (int*)alloc((size_t)Epad*4);
  unsigned short* xbf = (unsigned short*)alloc((size_t)N*256*2);
  unsigned short* qb  = (unsigned short*)alloc((size_t)N*256*2);
  char*           kvb = (char*)alloc((size_t)N*1024);
  unsigned short* xb  = (unsigned short*)alloc((size_t)N*256*2);
  unsigned short* hbuf= (unsigned short*)alloc((size_t)N*256*2);
  (void)ws_size; (void)n_in; (void)out_size;

  // dtype flag + canonical bf16 x
  k_flag<<<1, 256, 0, stream>>>((const unsigned short*)d_in[0], flag);
  int n4 = (N * 256) / 4;
  k_cvt<<<(n4 + 255) / 256, 256, 0, stream>>>(d_in[0], xbf, n4, flag);

  // CSR build (dst-sorted, 4-aligned padded segments), parallel scan
  hipMemsetAsync(deg, 0, (size_t)N*4, stream);
  hipMemsetAsync(srcs, 0, (size_t)Epad*4, stream);   // pad slots -> node 0 (masked later)
  int eb = (E + 255) / 256;
  int nbk = (N + 1023) / 1024;
  k_deg<<<eb, 256, 0, stream>>>(ei, E, N, deg);
  k_bsum<<<nbk, 256, 0, stream>>>(deg, N, bsum);
  k_bscan<<<1, 64, 0, stream>>>(bsum, nbk, boff, rowptr, N);
  k_rowptr<<<nbk, 256, 0, stream>>>(deg, boff, N, rowptr, cursor);
  k_scatter<<<eb, 256, 0, stream>>>(ei, E, N, Epad, cursor, srcs);

  // pack transposed fused weights + biases
  k_pack<<<1024, 256, 0, stream>>>(d_in[2],  d_in[3],  d_in[4],  d_in[5],  d_in[6],  d_in[7],  d_in[8],  d_in[9],  WT1, bias1, 256, 256, 256, flag);
  k_pack<<<1024, 256, 0, stream>>>(d_in[11], d_in[12], d_in[13], d_in[14], d_in[15], d_in[16], d_in[17], d_in[18], WT2, bias2, 256, 256, 256, flag);
  k_pack<<< 256, 256, 0, stream>>>(d_in[20], d_in[21], d_in[22], d_in[23], d_in[24], d_in[25], d_in[26], d_in[27], WT3, bias3,  64,   8, 256, flag);

  int rb = (N + 63) / 64;
  int nb = (N + 3) / 4;
  // layer 1
  k_gemm<<<rb * 4, 256, 0, stream>>>(xbf, WT1, bias1, qb, kvb, xb, N, 1024, 8);
  k_attn<<<nb, 256, 0, stream>>>(qb, kvb, xb, rowptr, deg, srcs, d_in[10], d_in[29], d_in[30], hbuf, N, E, flag);
  // layer 2
  k_gemm<<<rb * 4, 256, 0, stream>>>(hbuf, WT2, bias2, qb, kvb, xb, N, 1024, 8);
  k_attn<<<nb, 256, 0, stream>>>(qb, kvb, xb, rowptr, deg, srcs, d_in[19], d_in[31], d_in[32], hbuf, N, E, flag);
  // layer 3
  k_gemm<<<rb, 256, 0, stream>>>(hbuf, WT3, bias3, qb, kvb, xb, N, 256, 6);
  k_final<<<nb, 256, 0, stream>>>(qb, kvb, xb, rowptr, deg, srcs, d_in[28], d_out, N, E, flag);
}